// Round 5
// baseline (411.837 us; speedup 1.0000x reference)
//
#include <hip/hip_runtime.h>
#include <hip/hip_bf16.h>
#include <cstddef>

// BS=8, NE=128, ENT=768, REL=768, RANK=256, OUT=256
// M = 131072 rows; rel row-major [b][i][j][768]
// ws: l1 [1024*256 f32] | l2 [1024*256 f32] | W3g [196608 bf16 frag] | Weg [65536 bf16 frag]
// Fragment-major B panels: flat = ((kq*256 + n)*4 + g)*8 + e (kq=k/32, g=(k/8)%4, e=k%8)
//
// fused_main structure (barrier-free K-loop):
//   GEMM1: acc1 = W3 (A, frag-major from L2/L1) x rel^T (B, wave-private LDS staging)
//          D1[row=n][col=m]: lane(g,c16) holds n = nf*16+g*4+r, m = c16 (wave's local row)
//   epilogue: prod = (l3+b3)*l1*l2, packed bf16 in regs
//   B2 = prod built by 64 ds_bpermute (in-register transpose of n-dim to k-role)
//   GEMM2: f = We (A, frag-major) x prod (B); two halves of 8 outfrags, half0 -> wave LDS
//   LN: wave-local (shfl_xor over g), store straight from regs.

typedef __attribute__((ext_vector_type(8))) short short8;
typedef __attribute__((ext_vector_type(4))) float f32x4;

__device__ __forceinline__ unsigned short f2bf(float x) {
  union { float f; unsigned u; } v; v.f = x;
  unsigned r = (v.u + 0x7FFFu + ((v.u >> 16) & 1u)) >> 16;  // RNE
  return (unsigned short)r;
}
__device__ __forceinline__ unsigned short cvt1(float x) {
  return __bfloat16_as_ushort(__float2bfloat16(x));
}
__device__ __forceinline__ f32x4 mfma16(short8 a, short8 b, f32x4 c) {
  return __builtin_amdgcn_mfma_f32_16x16x32_bf16(a, b, c, 0, 0, 0);
}
__device__ __forceinline__ short8 pk8(f32x4 x, f32x4 y) {
  short8 s;
  s[0] = (short)cvt1(x[0]); s[1] = (short)cvt1(x[1]);
  s[2] = (short)cvt1(x[2]); s[3] = (short)cvt1(x[3]);
  s[4] = (short)cvt1(y[0]); s[5] = (short)cvt1(y[1]);
  s[6] = (short)cvt1(y[2]); s[7] = (short)cvt1(y[3]);
  return s;
}

// ---------------- prep (grid 1280) -------------------------------------------
__global__ __launch_bounds__(256) void prep_all(
    const float* __restrict__ sub, const float* __restrict__ obj,
    const float* __restrict__ W1, const float* __restrict__ b1,
    const float* __restrict__ W2, const float* __restrict__ b2,
    const float* __restrict__ W3, const float* __restrict__ We,
    float* __restrict__ l1p, float* __restrict__ l2p,
    unsigned short* __restrict__ W3g, unsigned short* __restrict__ Weg) {
  const int tid = threadIdx.x;
  if (blockIdx.x >= 256) {
    int idx = (blockIdx.x - 256) * 256 + tid;
    if (idx < 196608) {
      int n = idx / 768, k = idx % 768;
      int f = ((k >> 5) * 256 + n) * 32 + ((k >> 3) & 3) * 8 + (k & 7);
      W3g[f] = f2bf(W3[idx]);
    }
    int j = idx - 196608;
    if (j >= 0 && j < 65536) {
      int n = j / 256, k = j % 256;
      int f = ((k >> 5) * 256 + n) * 32 + ((k >> 3) & 3) * 8 + (k & 7);
      Weg[f] = f2bf(We[j]);
    }
    return;
  }
  const int half = blockIdx.x >> 7;
  const float* x = half ? obj : sub;
  const float* W = half ? W2 : W1;
  const float* bias = half ? b2 : b1;
  float* outp = half ? l2p : l1p;

  __shared__ float xs[8][768];
  const int R0 = (blockIdx.x & 127) * 8;
  #pragma unroll
  for (int c = 0; c < 6; ++c) {
    int f4i = c * 256 + tid;
    int row = f4i / 192;
    int c4 = f4i % 192;
    *(float4*)&xs[row][c4 * 4] = *(const float4*)&x[(size_t)(R0 + row) * 768 + c4 * 4];
  }
  __syncthreads();
  const int col = tid;
  const float* Wr = W + (size_t)col * 768;
  float a[8] = {0.f, 0.f, 0.f, 0.f, 0.f, 0.f, 0.f, 0.f};
  for (int k4 = 0; k4 < 192; ++k4) {
    float4 wv = *(const float4*)&Wr[k4 * 4];
    #pragma unroll
    for (int r = 0; r < 8; ++r) {
      float4 xv = *(const float4*)&xs[r][k4 * 4];
      a[r] += wv.x * xv.x + wv.y * xv.y + wv.z * xv.z + wv.w * xv.w;
    }
  }
  float bb = bias[col];
  #pragma unroll
  for (int r = 0; r < 8; ++r)
    outp[(size_t)(R0 + r) * 256 + col] = a[r] + bb;
}

// ---------------- fused main -------------------------------------------------
__global__ __launch_bounds__(256, 4) void fused_main(
    const float* __restrict__ rel, const float* __restrict__ l1p,
    const float* __restrict__ l2p, const unsigned short* __restrict__ W3g,
    const unsigned short* __restrict__ Weg, const float* __restrict__ b3,
    const float* __restrict__ be, const float* __restrict__ lng,
    const float* __restrict__ lnb, float* __restrict__ out) {
  // per-wave private LDS, 8KB each; no cross-wave sharing -> no barriers
  __shared__ union WavePriv {
    unsigned short stg[2][16][64];  // 4KB: [buf][row][col bf16], 16B-unit swizzle pos=u^(row&7)
    float fbuf[8][64][4];           // 8KB: GEMM2 half0 f-values (with +be)
  } u[4];

  const int tid = threadIdx.x;
  const int wave = tid >> 6, lane = tid & 63;
  const int g = lane >> 4, c16 = lane & 15;

  const int R0 = blockIdx.x * 64;
  const int b = R0 >> 14;
  const int rem = R0 & 16383;
  const int i = rem >> 7;
  const int j0 = rem & 127;

  const float* relW = rel + (size_t)((b * 128 + i) * 128 + j0 + wave * 16) * 768;
  const float* l2row = l2p + (size_t)(b * 128 + j0 + wave * 16 + c16) * 256;
  const float* l1row = l1p + (size_t)(b * 128 + i) * 256;

  // A(rel)-staging geometry: lane loads row ar=lane>>2, f32 cols ac..ac+15
  const int ar = lane >> 2, ac = (lane & 3) * 16;
  const float* aptr = relW + (size_t)ar * 768 + ac;
  const int u0 = (lane & 3) * 2;
  unsigned short* st0 = &u[wave].stg[0][ar][((u0 ^ (ar & 7)) * 8)];
  unsigned short* st1 = &u[wave].stg[0][ar][(((u0 + 1) ^ (ar & 7)) * 8)];
  const int bufStride = 16 * 64;  // ushorts per buf

  f32x4 acc1[16] = {};

  // prologue: stage tile 0
  {
    f32x4 a0 = *(const f32x4*)(aptr);
    f32x4 a1 = *(const f32x4*)(aptr + 4);
    f32x4 a2 = *(const f32x4*)(aptr + 8);
    f32x4 a3 = *(const f32x4*)(aptr + 12);
    *(short8*)st0 = pk8(a0, a1);
    *(short8*)st1 = pk8(a2, a3);
  }

  const unsigned short* stR = &u[wave].stg[0][c16][0];
  const int rd0 = ((0 * 4 + g) ^ (c16 & 7)) * 8;
  const int rd1 = ((1 * 4 + g) ^ (c16 & 7)) * 8;

  for (int ks = 0; ks < 12; ++ks) {
    const int boff = (ks & 1) * bufStride;
    f32x4 a0, a1, a2, a3;
    if (ks < 11) {
      const float* p = aptr + (ks + 1) * 64;
      a0 = *(const f32x4*)(p);
      a1 = *(const f32x4*)(p + 4);
      a2 = *(const f32x4*)(p + 8);
      a3 = *(const f32x4*)(p + 12);
    }
    short8 bf0 = *(const short8*)(stR + boff + rd0);
    short8 bf1 = *(const short8*)(stR + boff + rd1);
    const unsigned short* w3a = W3g + ((size_t)(ks * 2) * 256 + c16) * 32 + g * 8;
    #pragma unroll
    for (int nf = 0; nf < 16; ++nf) {
      short8 af0 = *(const short8*)(w3a + nf * 512);
      acc1[nf] = mfma16(af0, bf0, acc1[nf]);
      short8 af1 = *(const short8*)(w3a + 8192 + nf * 512);
      acc1[nf] = mfma16(af1, bf1, acc1[nf]);
    }
    if (ks < 11) {
      const int noff = ((ks + 1) & 1) * bufStride;
      *(short8*)(st0 + noff) = pk8(a0, a1);
      *(short8*)(st1 + noff) = pk8(a2, a3);
    }
  }

  // ---- epilogue 1: prod = (l3 + b3) * l1 * l2, pack to bf16 pairs ----
  unsigned int prodpk[16][2];
  #pragma unroll
  for (int nf = 0; nf < 16; ++nf) {
    f32x4 l1v = *(const f32x4*)&l1row[nf * 16 + g * 4];
    f32x4 b3v = *(const f32x4*)&b3[nf * 16 + g * 4];
    f32x4 l2v = *(const f32x4*)&l2row[nf * 16 + g * 4];
    f32x4 p;
    #pragma unroll
    for (int r = 0; r < 4; ++r)
      p[r] = (acc1[nf][r] + b3v[r]) * l1v[r] * l2v[r];
    prodpk[nf][0] = (unsigned)cvt1(p[0]) | ((unsigned)cvt1(p[1]) << 16);
    prodpk[nf][1] = (unsigned)cvt1(p[2]) | ((unsigned)cvt1(p[3]) << 16);
  }

  // ---- build B2 fragments in-register (transpose n->k role) ----
  // dst lane(g,c16), kchunk k: B2[col=c16][k'=g*8+e] = prod[n=k*32+g*8+e][m=c16]
  // src holder of n: nf=(n>>4), lane g'=(n>>2)&3, r=n&3 -> for dst: nf=k*2+(g>>1),
  // g'=(g&1)*2+(e>>2), r=e&3. prodpk[nf][h] holds r-pair (2h,2h+1).
  int b2f[8][4];
  const int srcbase = ((g & 1) * 2) * 16 + c16;
  #pragma unroll
  for (int k = 0; k < 8; ++k) {
    #pragma unroll
    for (int q = 0; q < 4; ++q) {
      const int h = q & 1;
      const int src = srcbase + (q >> 1) * 16;
      int s0 = __shfl((int)prodpk[k * 2][h], src);
      int s1 = __shfl((int)prodpk[k * 2 + 1][h], src);
      b2f[k][q] = (g >> 1) ? s1 : s0;
    }
  }

  // ---- GEMM2 in two halves of 8 outfrags ----
  const unsigned short* weA = Weg + (size_t)c16 * 32 + g * 8;  // + k*8192 + of*512
  float s1 = 0.f, s2 = 0.f;
  {
    f32x4 facc[8] = {};
    #pragma unroll
    for (int k = 0; k < 8; ++k) {
      short8 b2 = *(const short8*)&b2f[k][0];
      #pragma unroll
      for (int of = 0; of < 8; ++of) {
        short8 a2 = *(const short8*)(weA + k * 8192 + of * 512);
        facc[of] = mfma16(a2, b2, facc[of]);
      }
    }
    #pragma unroll
    for (int of = 0; of < 8; ++of) {
      f32x4 bev = *(const f32x4*)&be[of * 16 + g * 4];
      f32x4 v;
      #pragma unroll
      for (int r = 0; r < 4; ++r) {
        v[r] = facc[of][r] + bev[r];
        s1 += v[r]; s2 += v[r] * v[r];
      }
      *(f32x4*)&u[wave].fbuf[of][lane][0] = v;  // park half0
    }
  }
  f32x4 facc[8] = {};
  #pragma unroll
  for (int k = 0; k < 8; ++k) {
    short8 b2 = *(const short8*)&b2f[k][0];
    #pragma unroll
    for (int of = 0; of < 8; ++of) {
      short8 a2 = *(const short8*)(weA + k * 8192 + (8 + of) * 512);
      facc[of] = mfma16(a2, b2, facc[of]);
    }
  }
  #pragma unroll
  for (int of = 0; of < 8; ++of) {
    f32x4 bev = *(const f32x4*)&be[(8 + of) * 16 + g * 4];
    #pragma unroll
    for (int r = 0; r < 4; ++r) {
      facc[of][r] += bev[r];
      s1 += facc[of][r]; s2 += facc[of][r] * facc[of][r];
    }
  }

  // ---- LN stats: reduce across g-groups (same c16) ----
  s1 += __shfl_xor(s1, 16); s1 += __shfl_xor(s1, 32);
  s2 += __shfl_xor(s2, 16); s2 += __shfl_xor(s2, 32);
  const float mu = s1 * 0.00390625f;
  const float rs = rsqrtf(s2 * 0.00390625f - mu * mu + 1e-6f);

  float* orow = out + (size_t)(R0 + wave * 16 + c16) * 256;
  #pragma unroll
  for (int of = 0; of < 8; ++of) {  // half1 from regs
    f32x4 gv = *(const f32x4*)&lng[(8 + of) * 16 + g * 4];
    f32x4 bv = *(const f32x4*)&lnb[(8 + of) * 16 + g * 4];
    f32x4 w;
    #pragma unroll
    for (int r = 0; r < 4; ++r) w[r] = (facc[of][r] - mu) * rs * gv[r] + bv[r];
    *(f32x4*)&orow[(8 + of) * 16 + g * 4] = w;
  }
  #pragma unroll
  for (int of = 0; of < 8; ++of) {  // half0 from LDS
    f32x4 v = *(const f32x4*)&u[wave].fbuf[of][lane][0];
    f32x4 gv = *(const f32x4*)&lng[of * 16 + g * 4];
    f32x4 bv = *(const f32x4*)&lnb[of * 16 + g * 4];
    f32x4 w;
    #pragma unroll
    for (int r = 0; r < 4; ++r) w[r] = (v[r] - mu) * rs * gv[r] + bv[r];
    *(f32x4*)&orow[of * 16 + g * 4] = w;
  }
}

extern "C" void kernel_launch(void* const* d_in, const int* in_sizes, int n_in,
                              void* d_out, int out_size, void* d_ws, size_t ws_size,
                              hipStream_t stream) {
  const float* sub = (const float*)d_in[0];
  const float* obj = (const float*)d_in[1];
  const float* rel = (const float*)d_in[2];
  const float* W1 = (const float*)d_in[3];
  const float* b1 = (const float*)d_in[4];
  const float* W2 = (const float*)d_in[5];
  const float* b2 = (const float*)d_in[6];
  const float* W3 = (const float*)d_in[7];
  const float* b3 = (const float*)d_in[8];
  const float* We = (const float*)d_in[9];
  const float* be = (const float*)d_in[10];
  const float* lng = (const float*)d_in[11];
  const float* lnb = (const float*)d_in[12];
  float* out = (float*)d_out;

  float* ws = (float*)d_ws;
  float* l1p = ws;
  float* l2p = ws + 262144;
  unsigned short* W3g = (unsigned short*)(ws + 524288);
  unsigned short* Weg = W3g + 196608;

  prep_all<<<1280, 256, 0, stream>>>(sub, obj, W1, b1, W2, b2, W3, We, l1p, l2p, W3g, Weg);
  fused_main<<<2048, 256, 0, stream>>>(rel, l1p, l2p, W3g, Weg, b3, be, lng, lnb, out);
}

// Round 6
// 319.912 us; speedup vs baseline: 1.2873x; 1.2873x over previous
//
#include <hip/hip_runtime.h>
#include <hip/hip_bf16.h>
#include <cstddef>

// BS=8, NE=128, ENT=768, REL=768, RANK=256, OUT=256
// M = 131072 rows; rel row-major [b][i][j][768]
// ws: l1 [1024*256 f32] | l2 [1024*256 f32] | W3g [196608 bf16 frag] | Weg [65536 bf16 frag]
// Fragment-major B panels: flat = ((kq*256 + n)*4 + g)*8 + e (kq=k/32, g=(k/8)%4, e=k%8)
//
// fused_main: GEMM1 K-loop is LDS-free and barrier-free:
//   A(rel) loaded per-lane straight from global in MFMA fragment layout
//   (row=fm*16+c16, k=kq*32+g*8), f32->bf16 in registers; zero redundancy.
//   B(W3g) fragment-major 1KB coalesced loads, L2-resident.
//   Symmetric depth-1 double-buffer {A,B} per half-tile: vmcnt FIFO holds one
//   generation, waits are counted, never a barrier drain (R5 lesson: vmcnt
//   retires IN ORDER - never interleave fast loads behind slow ones without
//   a full generation of distance).
// Epilogue: prod -> bf16 swizzled LDS tile, 1 barrier; GEMM2 from LDS + Weg;
// cross-wave LN via LDS partials (verified R2 path).

typedef __attribute__((ext_vector_type(8))) short short8;
typedef __attribute__((ext_vector_type(4))) float f32x4;

__device__ __forceinline__ unsigned short f2bf(float x) {
  union { float f; unsigned u; } v; v.f = x;
  unsigned r = (v.u + 0x7FFFu + ((v.u >> 16) & 1u)) >> 16;  // RNE
  return (unsigned short)r;
}
__device__ __forceinline__ unsigned short cvt1(float x) {
  return __bfloat16_as_ushort(__float2bfloat16(x));  // pairs to v_cvt_pk_bf16_f32
}
__device__ __forceinline__ f32x4 mfma16(short8 a, short8 b, f32x4 c) {
  return __builtin_amdgcn_mfma_f32_16x16x32_bf16(a, b, c, 0, 0, 0);
}
__device__ __forceinline__ short8 pk8(f32x4 x, f32x4 y) {
  short8 s;
  s[0] = (short)cvt1(x[0]); s[1] = (short)cvt1(x[1]);
  s[2] = (short)cvt1(x[2]); s[3] = (short)cvt1(x[3]);
  s[4] = (short)cvt1(y[0]); s[5] = (short)cvt1(y[1]);
  s[6] = (short)cvt1(y[2]); s[7] = (short)cvt1(y[3]);
  return s;
}

// ---------------- prep (grid 1280) -------------------------------------------
__global__ __launch_bounds__(256) void prep_all(
    const float* __restrict__ sub, const float* __restrict__ obj,
    const float* __restrict__ W1, const float* __restrict__ b1,
    const float* __restrict__ W2, const float* __restrict__ b2,
    const float* __restrict__ W3, const float* __restrict__ We,
    float* __restrict__ l1p, float* __restrict__ l2p,
    unsigned short* __restrict__ W3g, unsigned short* __restrict__ Weg) {
  const int tid = threadIdx.x;
  if (blockIdx.x >= 256) {
    int idx = (blockIdx.x - 256) * 256 + tid;
    if (idx < 196608) {
      int n = idx / 768, k = idx % 768;
      int f = ((k >> 5) * 256 + n) * 32 + ((k >> 3) & 3) * 8 + (k & 7);
      W3g[f] = f2bf(W3[idx]);
    }
    int j = idx - 196608;
    if (j >= 0 && j < 65536) {
      int n = j / 256, k = j % 256;
      int f = ((k >> 5) * 256 + n) * 32 + ((k >> 3) & 3) * 8 + (k & 7);
      Weg[f] = f2bf(We[j]);
    }
    return;
  }
  const int half = blockIdx.x >> 7;
  const float* x = half ? obj : sub;
  const float* W = half ? W2 : W1;
  const float* bias = half ? b2 : b1;
  float* outp = half ? l2p : l1p;

  __shared__ float xs[8][768];
  const int R0 = (blockIdx.x & 127) * 8;
  #pragma unroll
  for (int c = 0; c < 6; ++c) {
    int f4i = c * 256 + tid;
    int row = f4i / 192;
    int c4 = f4i % 192;
    *(float4*)&xs[row][c4 * 4] = *(const float4*)&x[(size_t)(R0 + row) * 768 + c4 * 4];
  }
  __syncthreads();
  const int col = tid;
  const float* Wr = W + (size_t)col * 768;
  float a[8] = {0.f, 0.f, 0.f, 0.f, 0.f, 0.f, 0.f, 0.f};
  for (int k4 = 0; k4 < 192; ++k4) {
    float4 wv = *(const float4*)&Wr[k4 * 4];
    #pragma unroll
    for (int r = 0; r < 8; ++r) {
      float4 xv = *(const float4*)&xs[r][k4 * 4];
      a[r] += wv.x * xv.x + wv.y * xv.y + wv.z * xv.z + wv.w * xv.w;
    }
  }
  float bb = bias[col];
  #pragma unroll
  for (int r = 0; r < 8; ++r)
    outp[(size_t)(R0 + r) * 256 + col] = a[r] + bb;
}

// ---------------- fused main -------------------------------------------------
__global__ __launch_bounds__(256) void fused_main(
    const float* __restrict__ rel, const float* __restrict__ l1p,
    const float* __restrict__ l2p, const unsigned short* __restrict__ W3g,
    const unsigned short* __restrict__ Weg, const float* __restrict__ b3,
    const float* __restrict__ be, const float* __restrict__ lng,
    const float* __restrict__ lnb, float* __restrict__ out) {
  __shared__ unsigned short prod[64][256];  // 32KB, XOR-swizzled
  __shared__ float l1s[256], b3s[256], bes[256], gs[256], bsh[256];
  __shared__ float ps[64][4], pq[64][4], mus[64], rss[64];

  const int tid = threadIdx.x;
  const int wave = tid >> 6, lane = tid & 63;
  const int g = lane >> 4, c16 = lane & 15;

  const int R0 = blockIdx.x * 64;
  const int b = R0 >> 14;
  const int rem = R0 & 16383;
  const int i = rem >> 7;
  const int j0 = rem & 127;  // 0 or 64

  const float* relBase = rel + (size_t)((b * 128 + i) * 128 + j0) * 768;

  l1s[tid] = l1p[(b * 128 + i) * 256 + tid];
  b3s[tid] = b3[tid];
  bes[tid] = be[tid];
  gs[tid] = lng[tid];
  bsh[tid] = lnb[tid];

  // A: lane owns rows fm*16+c16, k-slice g*8..g*8+7 of each 32-wide half-tile
  const float* ap0 = relBase + (size_t)c16 * 768 + g * 8;
  // B: fragment-major W3g; per-lane base, fn stride 512, kq stride 8192 (ushorts)
  const unsigned short* bp = W3g + (wave * 64 + c16) * 32 + g * 8;

  f32x4 acc1[4][4] = {};
  f32x4 A0[4][2], A1[4][2];
  short8 B0[4], B1[4];

#define PRE(A_, B_, KQ)                                                        \
  {                                                                            \
    _Pragma("unroll") for (int fn = 0; fn < 4; ++fn)                           \
        B_[fn] = *(const short8*)(bp + (size_t)(KQ) * 8192 + fn * 512);        \
    _Pragma("unroll") for (int fm = 0; fm < 4; ++fm) {                         \
      const float* p = ap0 + fm * (16 * 768) + (KQ) * 32;                      \
      A_[fm][0] = *(const f32x4*)p;                                            \
      A_[fm][1] = *(const f32x4*)(p + 4);                                      \
    }                                                                          \
  }

#define CMP(A_, B_)                                                            \
  {                                                                            \
    short8 ah[4];                                                              \
    _Pragma("unroll") for (int fm = 0; fm < 4; ++fm)                           \
        ah[fm] = pk8(A_[fm][0], A_[fm][1]);                                    \
    _Pragma("unroll") for (int fn = 0; fn < 4; ++fn)                           \
        _Pragma("unroll") for (int fm = 0; fm < 4; ++fm)                       \
            acc1[fm][fn] = mfma16(ah[fm], B_[fn], acc1[fm][fn]);               \
  }

  PRE(A0, B0, 0);
  for (int ks = 0; ks < 11; ++ks) {
    PRE(A1, B1, 2 * ks + 1);
    __builtin_amdgcn_sched_barrier(0);
    CMP(A0, B0);
    __builtin_amdgcn_sched_barrier(0);
    PRE(A0, B0, 2 * ks + 2);
    __builtin_amdgcn_sched_barrier(0);
    CMP(A1, B1);
    __builtin_amdgcn_sched_barrier(0);
  }
  PRE(A1, B1, 23);
  __builtin_amdgcn_sched_barrier(0);
  CMP(A0, B0);
  CMP(A1, B1);

  __syncthreads();  // l1s/b3s/... visible; all waves past K-loop

  // ---- epilogue 1: prod = (l3 + b3) * l1 * l2 -> bf16 swizzled LDS ----
  #pragma unroll
  for (int fm = 0; fm < 4; ++fm) {
    #pragma unroll
    for (int r = 0; r < 4; ++r) {
      const int m = fm * 16 + g * 4 + r;
      const float* l2row = l2p + (size_t)(b * 128 + j0 + m) * 256;
      #pragma unroll
      for (int fn = 0; fn < 4; ++fn) {
        const int col = wave * 64 + fn * 16 + c16;
        float v = (acc1[fm][fn][r] + b3s[col]) * l1s[col] * l2row[col];
        prod[m][col ^ ((m & 7) << 3)] = f2bf(v);
      }
    }
  }
  __syncthreads();

  // ---- GEMM2: f = prod @ Web^T (Weg fragment-major) ----
  f32x4 acc2[4][4] = {};
  #pragma unroll
  for (int kk = 0; kk < 8; ++kk) {
    short8 a2[4];
    #pragma unroll
    for (int fm = 0; fm < 4; ++fm) {
      const int m = fm * 16 + c16;
      a2[fm] = *(const short8*)&prod[m][(kk * 32 + g * 8) ^ ((m & 7) << 3)];
    }
    #pragma unroll
    for (int fn = 0; fn < 4; ++fn) {
      const int n = wave * 64 + fn * 16 + c16;
      short8 bfr = *(const short8*)&Weg[((kk * 256 + n) * 4 + g) * 8];
      #pragma unroll
      for (int fm = 0; fm < 4; ++fm)
        acc2[fm][fn] = mfma16(a2[fm], bfr, acc2[fm][fn]);
    }
  }

  // ---- LN stats: per-row sum/sumsq; 16-lane shfl reduce + cross-wave LDS ----
  #pragma unroll
  for (int fm = 0; fm < 4; ++fm) {
    #pragma unroll
    for (int r = 0; r < 4; ++r) {
      float s1 = 0.f, s2 = 0.f;
      #pragma unroll
      for (int fn = 0; fn < 4; ++fn) {
        const int col = wave * 64 + fn * 16 + c16;
        float v = acc2[fm][fn][r] + bes[col];
        s1 += v; s2 += v * v;
      }
      #pragma unroll
      for (int off = 1; off < 16; off <<= 1) {
        s1 += __shfl_xor(s1, off);
        s2 += __shfl_xor(s2, off);
      }
      if (c16 == 0) {
        const int m = fm * 16 + g * 4 + r;
        ps[m][wave] = s1; pq[m][wave] = s2;
      }
    }
  }
  __syncthreads();
  if (tid < 64) {
    float s = ps[tid][0] + ps[tid][1] + ps[tid][2] + ps[tid][3];
    float q = pq[tid][0] + pq[tid][1] + pq[tid][2] + pq[tid][3];
    float mu = s * 0.00390625f;
    float var = q * 0.00390625f - mu * mu;
    mus[tid] = mu;
    rss[tid] = rsqrtf(var + 1e-6f);
  }
  __syncthreads();

  // ---- store: (f - mu)*rs*g + b ----
  #pragma unroll
  for (int fm = 0; fm < 4; ++fm) {
    #pragma unroll
    for (int r = 0; r < 4; ++r) {
      const int m = fm * 16 + g * 4 + r;
      const float mu = mus[m], rs = rss[m];
      float* orow = out + (size_t)(R0 + m) * 256;
      #pragma unroll
      for (int fn = 0; fn < 4; ++fn) {
        const int col = wave * 64 + fn * 16 + c16;
        float v = acc2[fm][fn][r] + bes[col];
        orow[col] = (v - mu) * rs * gs[col] + bsh[col];
      }
    }
  }
#undef PRE
#undef CMP
}

extern "C" void kernel_launch(void* const* d_in, const int* in_sizes, int n_in,
                              void* d_out, int out_size, void* d_ws, size_t ws_size,
                              hipStream_t stream) {
  const float* sub = (const float*)d_in[0];
  const float* obj = (const float*)d_in[1];
  const float* rel = (const float*)d_in[2];
  const float* W1 = (const float*)d_in[3];
  const float* b1 = (const float*)d_in[4];
  const float* W2 = (const float*)d_in[5];
  const float* b2 = (const float*)d_in[6];
  const float* W3 = (const float*)d_in[7];
  const float* b3 = (const float*)d_in[8];
  const float* We = (const float*)d_in[9];
  const float* be = (const float*)d_in[10];
  const float* lng = (const float*)d_in[11];
  const float* lnb = (const float*)d_in[12];
  float* out = (float*)d_out;

  float* ws = (float*)d_ws;
  float* l1p = ws;
  float* l2p = ws + 262144;
  unsigned short* W3g = (unsigned short*)(ws + 524288);
  unsigned short* Weg = W3g + 196608;

  prep_all<<<1280, 256, 0, stream>>>(sub, obj, W1, b1, W2, b2, W3, We, l1p, l2p, W3g, Weg);
  fused_main<<<2048, 256, 0, stream>>>(rel, l1p, l2p, W3g, Weg, b3, be, lng, lnb, out);
}

// Round 7
// 283.574 us; speedup vs baseline: 1.4523x; 1.1281x over previous
//
#include <hip/hip_runtime.h>
#include <hip/hip_bf16.h>
#include <cstddef>

// BS=8, NE=128, ENT=768, REL=768, RANK=256, OUT=256
// M = 131072 rows; rel row-major [b][i][j][768]
// ws: l1 [1024*256 f32] | l2 [1024*256 f32] | W3g [196608 bf16 frag] | Weg [65536 bf16 frag]
// Fragment-major B panels: flat = ((kq*256 + n)*4 + g)*8 + e (kq=k/32, g=(k/8)%4, e=k%8)
//
// fused_main (R3 structure + fixes):
//  - rel staged f32 via global_load_lds (linear dest), source pre-swizzled at
//    16B-unit granularity: LDS[r][u] = G[r][u ^ (r&7)] -> ds_read_b128 is 2-way max.
//  - B(W3g) double-buffered in regs, issued right after the staging ISSUE so each
//    vmcnt generation is [stage x4, B x8]; per-iter wait = vmcnt(12): retires
//    gen k fully, keeps gen k+1 in flight (R4/R5 FIFO lesson).
//  - 2 barriers/iter protect cross-wave LDS reuse.

typedef __attribute__((ext_vector_type(8))) short short8;
typedef __attribute__((ext_vector_type(4))) float f32x4;

__device__ __forceinline__ unsigned short f2bf(float x) {
  union { float f; unsigned u; } v; v.f = x;
  unsigned r = (v.u + 0x7FFFu + ((v.u >> 16) & 1u)) >> 16;  // RNE
  return (unsigned short)r;
}
__device__ __forceinline__ unsigned short cvt1(float x) {
  return __bfloat16_as_ushort(__float2bfloat16(x));  // pairs to v_cvt_pk_bf16_f32
}
__device__ __forceinline__ f32x4 mfma16(short8 a, short8 b, f32x4 c) {
  return __builtin_amdgcn_mfma_f32_16x16x32_bf16(a, b, c, 0, 0, 0);
}
__device__ __forceinline__ short8 pk8(f32x4 x, f32x4 y) {
  short8 s;
  s[0] = (short)cvt1(x[0]); s[1] = (short)cvt1(x[1]);
  s[2] = (short)cvt1(x[2]); s[3] = (short)cvt1(x[3]);
  s[4] = (short)cvt1(y[0]); s[5] = (short)cvt1(y[1]);
  s[6] = (short)cvt1(y[2]); s[7] = (short)cvt1(y[3]);
  return s;
}
__device__ __forceinline__ void gload_lds16(const float* g, float* l) {
  __builtin_amdgcn_global_load_lds((__attribute__((address_space(1))) void*)(g),
                                   (__attribute__((address_space(3))) void*)(l), 16, 0, 0);
}

// ---------------- prep (grid 1280) -------------------------------------------
__global__ __launch_bounds__(256) void prep_all(
    const float* __restrict__ sub, const float* __restrict__ obj,
    const float* __restrict__ W1, const float* __restrict__ b1,
    const float* __restrict__ W2, const float* __restrict__ b2,
    const float* __restrict__ W3, const float* __restrict__ We,
    float* __restrict__ l1p, float* __restrict__ l2p,
    unsigned short* __restrict__ W3g, unsigned short* __restrict__ Weg) {
  const int tid = threadIdx.x;
  if (blockIdx.x >= 256) {
    int idx = (blockIdx.x - 256) * 256 + tid;
    if (idx < 196608) {
      int n = idx / 768, k = idx % 768;
      int f = ((k >> 5) * 256 + n) * 32 + ((k >> 3) & 3) * 8 + (k & 7);
      W3g[f] = f2bf(W3[idx]);
    }
    int j = idx - 196608;
    if (j >= 0 && j < 65536) {
      int n = j / 256, k = j % 256;
      int f = ((k >> 5) * 256 + n) * 32 + ((k >> 3) & 3) * 8 + (k & 7);
      Weg[f] = f2bf(We[j]);
    }
    return;
  }
  const int half = blockIdx.x >> 7;
  const float* x = half ? obj : sub;
  const float* W = half ? W2 : W1;
  const float* bias = half ? b2 : b1;
  float* outp = half ? l2p : l1p;

  __shared__ float xs[8][768];
  const int R0 = (blockIdx.x & 127) * 8;
  #pragma unroll
  for (int c = 0; c < 6; ++c) {
    int f4i = c * 256 + tid;
    int row = f4i / 192;
    int c4 = f4i % 192;
    *(float4*)&xs[row][c4 * 4] = *(const float4*)&x[(size_t)(R0 + row) * 768 + c4 * 4];
  }
  __syncthreads();
  const int col = tid;
  const float* Wr = W + (size_t)col * 768;
  float a[8] = {0.f, 0.f, 0.f, 0.f, 0.f, 0.f, 0.f, 0.f};
  for (int k4 = 0; k4 < 192; ++k4) {
    float4 wv = *(const float4*)&Wr[k4 * 4];
    #pragma unroll
    for (int r = 0; r < 8; ++r) {
      float4 xv = *(const float4*)&xs[r][k4 * 4];
      a[r] += wv.x * xv.x + wv.y * xv.y + wv.z * xv.z + wv.w * xv.w;
    }
  }
  float bb = bias[col];
  #pragma unroll
  for (int r = 0; r < 8; ++r)
    outp[(size_t)(R0 + r) * 256 + col] = a[r] + bb;
}

// ---------------- fused main -------------------------------------------------
__global__ __launch_bounds__(256, 3) void fused_main(
    const float* __restrict__ rel, const float* __restrict__ l1p,
    const float* __restrict__ l2p, const unsigned short* __restrict__ W3g,
    const unsigned short* __restrict__ Weg, const float* __restrict__ b3,
    const float* __restrict__ be, const float* __restrict__ lng,
    const float* __restrict__ lnb, float* __restrict__ out) {
  __shared__ union U {
    float stgf[2][64][64];          // 32 KB staging, unit-swizzled source
    unsigned short prod[64][256];   // 32 KB
  } u;
  __shared__ float l1s[256], b3s[256], bes[256], gs[256], bsh[256];
  __shared__ float ps[64][4], pq[64][4], mus[64], rss[64];

  const int tid = threadIdx.x;
  const int wave = tid >> 6, lane = tid & 63;
  const int g = lane >> 4, c16 = lane & 15;

  // XCD-bijective swizzle (2048 % 8 == 0)
  const int bid = (blockIdx.x & 7) * 256 + (blockIdx.x >> 3);
  const int R0 = bid * 64;
  const int b = R0 >> 14;
  const int rem = R0 & 16383;
  const int i = rem >> 7;
  const int j0 = rem & 127;  // 0 or 64

  const float* relBase = rel + (size_t)((b * 128 + i) * 128 + j0) * 768;

  l1s[tid] = l1p[(b * 128 + i) * 256 + tid];
  b3s[tid] = b3[tid];
  bes[tid] = be[tid];
  gs[tid] = lng[tid];
  bsh[tid] = lnb[tid];

  // ---- staging geometry: wave covers rows wave*16..wave*16+15 in 4 chunks of 4.
  // lane: row-in-chunk sr = lane>>4, dest unit su = lane&15.
  // LDS[r][u] holds G[r][u ^ (r&7)] (16B units), so src unit = su ^ (r&7).
  const int sr = lane >> 4;
  const int su = lane & 15;
  const float* gsrc[4];
  #pragma unroll
  for (int q = 0; q < 4; ++q) {
    int r = (wave * 4 + q) * 4 + sr;
    gsrc[q] = relBase + (size_t)r * 768 + (size_t)((su ^ (r & 7)) * 4);
  }

  auto ISSUE = [&](int bufsel, int ks) {
    #pragma unroll
    for (int q = 0; q < 4; ++q)
      gload_lds16(gsrc[q] + ks * 64, &u.stgf[bufsel][(wave * 4 + q) * 4][0]);
  };

  // B fragments: W3g frag-major; per-lane base for n = wave*64 + fn*16 + c16
  const unsigned short* bp = W3g + (size_t)(wave * 64 + c16) * 32 + g * 8;
  short8 B0[8], B1[8];

  auto LOADB = [&](short8* B_, int ks) {
    #pragma unroll
    for (int sub = 0; sub < 2; ++sub)
      #pragma unroll
      for (int fn = 0; fn < 4; ++fn)
        B_[sub * 4 + fn] =
            *(const short8*)(bp + (size_t)(ks * 2 + sub) * 8192 + fn * 512);
  };

  f32x4 acc1[4][4] = {};

  auto COMPUTE = [&](int bufsel, const short8* B_) {
    #pragma unroll
    for (int sub = 0; sub < 2; ++sub) {
      short8 ah[4];
      #pragma unroll
      for (int fm = 0; fm < 4; ++fm) {
        const int r = fm * 16 + c16;
        const int s0 = sub * 8 + g * 2;  // source unit of the 8-f32 slice
        const int u0 = s0 ^ (r & 7), u1 = (s0 + 1) ^ (r & 7);
        f32x4 lo = *(const f32x4*)&u.stgf[bufsel][r][u0 * 4];
        f32x4 hi = *(const f32x4*)&u.stgf[bufsel][r][u1 * 4];
        ah[fm] = pk8(lo, hi);
      }
      #pragma unroll
      for (int fn = 0; fn < 4; ++fn)
        #pragma unroll
        for (int fm = 0; fm < 4; ++fm)
          acc1[fm][fn] = mfma16(ah[fm], B_[sub * 4 + fn], acc1[fm][fn]);
    }
  };

#define WAIT12 asm volatile("s_waitcnt vmcnt(12)" ::: "memory")
#define WAIT0 asm volatile("s_waitcnt vmcnt(0)" ::: "memory")
#define BAR __builtin_amdgcn_s_barrier()
#define SCHED0 __builtin_amdgcn_sched_barrier(0)

  // prologue: generation 0
  ISSUE(0, 0);
  LOADB(B0, 0);

  for (int kp = 0; kp < 5; ++kp) {
    ISSUE(1, 2 * kp + 1); LOADB(B1, 2 * kp + 1);
    WAIT12; BAR; SCHED0;
    COMPUTE(0, B0);        // ks = 2kp
    SCHED0; BAR; SCHED0;
    ISSUE(0, 2 * kp + 2); LOADB(B0, 2 * kp + 2);
    WAIT12; BAR; SCHED0;
    COMPUTE(1, B1);        // ks = 2kp+1
    SCHED0; BAR; SCHED0;
  }
  ISSUE(1, 11); LOADB(B1, 11);
  WAIT12; BAR; SCHED0;
  COMPUTE(0, B0);          // ks = 10
  SCHED0; BAR; SCHED0;
  WAIT0; BAR; SCHED0;
  COMPUTE(1, B1);          // ks = 11
  SCHED0;
  __syncthreads();         // all waves done with stgf before prod overwrite

  // ---- epilogue 1: prod = (l3 + b3) * l1 * l2 -> bf16 swizzled LDS ----
  #pragma unroll
  for (int fm = 0; fm < 4; ++fm) {
    #pragma unroll
    for (int r = 0; r < 4; ++r) {
      const int m = fm * 16 + g * 4 + r;
      const float* l2row = l2p + (size_t)(b * 128 + j0 + m) * 256;
      #pragma unroll
      for (int fn = 0; fn < 4; ++fn) {
        const int col = wave * 64 + fn * 16 + c16;
        float v = (acc1[fm][fn][r] + b3s[col]) * l1s[col] * l2row[col];
        u.prod[m][col ^ ((m & 7) << 3)] = f2bf(v);
      }
    }
  }
  __syncthreads();

  // ---- GEMM2: f = prod @ Web^T (Weg fragment-major) ----
  f32x4 acc2[4][4] = {};
  #pragma unroll
  for (int kk = 0; kk < 8; ++kk) {
    short8 a2[4];
    #pragma unroll
    for (int fm = 0; fm < 4; ++fm) {
      const int m = fm * 16 + c16;
      a2[fm] = *(const short8*)&u.prod[m][(kk * 32 + g * 8) ^ ((m & 7) << 3)];
    }
    #pragma unroll
    for (int fn = 0; fn < 4; ++fn) {
      const int n = wave * 64 + fn * 16 + c16;
      short8 bfr = *(const short8*)&Weg[(size_t)((kk * 256 + n) * 4 + g) * 8];
      #pragma unroll
      for (int fm = 0; fm < 4; ++fm)
        acc2[fm][fn] = mfma16(a2[fm], bfr, acc2[fm][fn]);
    }
  }

  // ---- LN stats: per-row sum/sumsq; 16-lane shfl reduce + cross-wave LDS ----
  #pragma unroll
  for (int fm = 0; fm < 4; ++fm) {
    #pragma unroll
    for (int r = 0; r < 4; ++r) {
      float s1 = 0.f, s2 = 0.f;
      #pragma unroll
      for (int fn = 0; fn < 4; ++fn) {
        const int col = wave * 64 + fn * 16 + c16;
        float v = acc2[fm][fn][r] + bes[col];
        s1 += v; s2 += v * v;
      }
      #pragma unroll
      for (int off = 1; off < 16; off <<= 1) {
        s1 += __shfl_xor(s1, off);
        s2 += __shfl_xor(s2, off);
      }
      if (c16 == 0) {
        const int m = fm * 16 + g * 4 + r;
        ps[m][wave] = s1; pq[m][wave] = s2;
      }
    }
  }
  __syncthreads();
  if (tid < 64) {
    float s = ps[tid][0] + ps[tid][1] + ps[tid][2] + ps[tid][3];
    float q = pq[tid][0] + pq[tid][1] + pq[tid][2] + pq[tid][3];
    float mu = s * 0.00390625f;
    float var = q * 0.00390625f - mu * mu;
    mus[tid] = mu;
    rss[tid] = rsqrtf(var + 1e-6f);
  }
  __syncthreads();

  // ---- store: (f - mu)*rs*g + b ----
  #pragma unroll
  for (int fm = 0; fm < 4; ++fm) {
    #pragma unroll
    for (int r = 0; r < 4; ++r) {
      const int m = fm * 16 + g * 4 + r;
      const float mu = mus[m], rs = rss[m];
      float* orow = out + (size_t)(R0 + m) * 256;
      #pragma unroll
      for (int fn = 0; fn < 4; ++fn) {
        const int col = wave * 64 + fn * 16 + c16;
        float v = acc2[fm][fn][r] + bes[col];
        orow[col] = (v - mu) * rs * gs[col] + bsh[col];
      }
    }
  }
#undef WAIT12
#undef WAIT0
#undef BAR
#undef SCHED0
}

extern "C" void kernel_launch(void* const* d_in, const int* in_sizes, int n_in,
                              void* d_out, int out_size, void* d_ws, size_t ws_size,
                              hipStream_t stream) {
  const float* sub = (const float*)d_in[0];
  const float* obj = (const float*)d_in[1];
  const float* rel = (const float*)d_in[2];
  const float* W1 = (const float*)d_in[3];
  const float* b1 = (const float*)d_in[4];
  const float* W2 = (const float*)d_in[5];
  const float* b2 = (const float*)d_in[6];
  const float* W3 = (const float*)d_in[7];
  const float* b3 = (const float*)d_in[8];
  const float* We = (const float*)d_in[9];
  const float* be = (const float*)d_in[10];
  const float* lng = (const float*)d_in[11];
  const float* lnb = (const float*)d_in[12];
  float* out = (float*)d_out;

  float* ws = (float*)d_ws;
  float* l1p = ws;
  float* l2p = ws + 262144;
  unsigned short* W3g = (unsigned short*)(ws + 524288);
  unsigned short* Weg = W3g + 196608;

  prep_all<<<1280, 256, 0, stream>>>(sub, obj, W1, b1, W2, b2, W3, We, l1p, l2p, W3g, Weg);
  fused_main<<<2048, 256, 0, stream>>>(rel, l1p, l2p, W3g, Weg, b3, be, lng, lnb, out);
}

// Round 8
// 211.663 us; speedup vs baseline: 1.9457x; 1.3397x over previous
//
#include <hip/hip_runtime.h>
#include <hip/hip_bf16.h>
#include <cstddef>

// BS=8, NE=128, ENT=768, REL=768, RANK=256, OUT=256
// M = 131072 rows; rel row-major [b][i][j][768]
// ws: l1 [1024*256 f32] | l2 [1024*256 f32] | W3g [196608 bf16 frag] | Weg [65536 bf16 frag]
// Fragment-major B panels: flat = ((kq*256 + n)*4 + g)*8 + e (kq=k/32, g=(k/8)%4, e=k%8)
//
// fused_main:
//  - A(rel) reg-staged: global f32x4 loads -> cvt_pk bf16 -> ds_write_b128 into
//    R2's measured-conflict-free layout: stg[buf][row][64] ushort, 16B-unit XOR
//    swizzle (unit' = unit ^ (row&7)); read side is one ds_read_b128 = ready frag.
//  - B(W3g) frag-major from L2, 8 loads issued FIRST each iter; A(k+1) issued
//    SECOND -> compiler's counted vmcnt retires B while A stays in flight
//    (R5/R7 FIFO lesson: never wait on a fast load queued behind a slow one).
//  - T14: A(k+1) issued before MFMA, written to LDS after -> full compute phase
//    of latency hiding. One __syncthreads()/iter (dbuf); VMEM queue empty there.

typedef __attribute__((ext_vector_type(8))) short short8;
typedef __attribute__((ext_vector_type(4))) float f32x4;

__device__ __forceinline__ unsigned short f2bf(float x) {
  union { float f; unsigned u; } v; v.f = x;
  unsigned r = (v.u + 0x7FFFu + ((v.u >> 16) & 1u)) >> 16;  // RNE
  return (unsigned short)r;
}
__device__ __forceinline__ unsigned short cvt1(float x) {
  return __bfloat16_as_ushort(__float2bfloat16(x));  // pairs to v_cvt_pk_bf16_f32
}
__device__ __forceinline__ f32x4 mfma16(short8 a, short8 b, f32x4 c) {
  return __builtin_amdgcn_mfma_f32_16x16x32_bf16(a, b, c, 0, 0, 0);
}
__device__ __forceinline__ short8 pk8(f32x4 x, f32x4 y) {
  short8 s;
  s[0] = (short)cvt1(x[0]); s[1] = (short)cvt1(x[1]);
  s[2] = (short)cvt1(x[2]); s[3] = (short)cvt1(x[3]);
  s[4] = (short)cvt1(y[0]); s[5] = (short)cvt1(y[1]);
  s[6] = (short)cvt1(y[2]); s[7] = (short)cvt1(y[3]);
  return s;
}

// ---------------- prep (grid 1280) -------------------------------------------
__global__ __launch_bounds__(256) void prep_all(
    const float* __restrict__ sub, const float* __restrict__ obj,
    const float* __restrict__ W1, const float* __restrict__ b1,
    const float* __restrict__ W2, const float* __restrict__ b2,
    const float* __restrict__ W3, const float* __restrict__ We,
    float* __restrict__ l1p, float* __restrict__ l2p,
    unsigned short* __restrict__ W3g, unsigned short* __restrict__ Weg) {
  const int tid = threadIdx.x;
  if (blockIdx.x >= 256) {
    int idx = (blockIdx.x - 256) * 256 + tid;
    if (idx < 196608) {
      int n = idx / 768, k = idx % 768;
      int f = ((k >> 5) * 256 + n) * 32 + ((k >> 3) & 3) * 8 + (k & 7);
      W3g[f] = f2bf(W3[idx]);
    }
    int j = idx - 196608;
    if (j >= 0 && j < 65536) {
      int n = j / 256, k = j % 256;
      int f = ((k >> 5) * 256 + n) * 32 + ((k >> 3) & 3) * 8 + (k & 7);
      Weg[f] = f2bf(We[j]);
    }
    return;
  }
  const int half = blockIdx.x >> 7;
  const float* x = half ? obj : sub;
  const float* W = half ? W2 : W1;
  const float* bias = half ? b2 : b1;
  float* outp = half ? l2p : l1p;

  __shared__ float xs[8][768];
  const int R0 = (blockIdx.x & 127) * 8;
  #pragma unroll
  for (int c = 0; c < 6; ++c) {
    int f4i = c * 256 + tid;
    int row = f4i / 192;
    int c4 = f4i % 192;
    *(float4*)&xs[row][c4 * 4] = *(const float4*)&x[(size_t)(R0 + row) * 768 + c4 * 4];
  }
  __syncthreads();
  const int col = tid;
  const float* Wr = W + (size_t)col * 768;
  float a[8] = {0.f, 0.f, 0.f, 0.f, 0.f, 0.f, 0.f, 0.f};
  for (int k4 = 0; k4 < 192; ++k4) {
    float4 wv = *(const float4*)&Wr[k4 * 4];
    #pragma unroll
    for (int r = 0; r < 8; ++r) {
      float4 xv = *(const float4*)&xs[r][k4 * 4];
      a[r] += wv.x * xv.x + wv.y * xv.y + wv.z * xv.z + wv.w * xv.w;
    }
  }
  float bb = bias[col];
  #pragma unroll
  for (int r = 0; r < 8; ++r)
    outp[(size_t)(R0 + r) * 256 + col] = a[r] + bb;
}

// ---------------- fused main -------------------------------------------------
__global__ __launch_bounds__(256, 4) void fused_main(
    const float* __restrict__ rel, const float* __restrict__ l1p,
    const float* __restrict__ l2p, const unsigned short* __restrict__ W3g,
    const unsigned short* __restrict__ Weg, const float* __restrict__ b3,
    const float* __restrict__ be, const float* __restrict__ lng,
    const float* __restrict__ lnb, float* __restrict__ out) {
  __shared__ union U {
    unsigned short stg[2][64][64];  // 16 KB bf16 staging (R2 layout, clean)
    unsigned short prod[64][256];   // 32 KB
  } u;
  __shared__ float l1s[256], b3s[256], bes[256], gs[256], bsh[256];
  __shared__ float ps[64][4], pq[64][4], mus[64], rss[64];

  const int tid = threadIdx.x;
  const int wave = tid >> 6, lane = tid & 63;
  const int g = lane >> 4, c16 = lane & 15;

  // XCD-bijective swizzle (2048 % 8 == 0)
  const int bid = (blockIdx.x & 7) * 256 + (blockIdx.x >> 3);
  const int R0 = bid * 64;
  const int b = R0 >> 14;
  const int rem = R0 & 16383;
  const int i = rem >> 7;
  const int j0 = rem & 127;  // 0 or 64

  const float* relBase = rel + (size_t)((b * 128 + i) * 128 + j0) * 768;

  l1s[tid] = l1p[(b * 128 + i) * 256 + tid];
  b3s[tid] = b3[tid];
  bes[tid] = be[tid];
  gs[tid] = lng[tid];
  bsh[tid] = lnb[tid];

  // ---- staging geometry: wave owns rows wave*16 .. wave*16+15.
  // lane: row rr = wave*16 + (lane>>2), 16-f32 chunk c4 = lane&3.
  // LDS ushort row [64]: 8 units of 16B; write units (c4*2+h) ^ (rr&7).
  const int sr4 = lane >> 2, c4 = lane & 3;
  const int rr = wave * 16 + sr4;
  const float* aG = relBase + (size_t)rr * 768 + c4 * 16;
  unsigned short* stW0 = &u.stg[0][rr][((c4 * 2) ^ (rr & 7)) * 8];
  unsigned short* stW1 = &u.stg[0][rr][((c4 * 2 + 1) ^ (rr & 7)) * 8];

  // B: fragment-major W3g; n = wave*64 + fn*16 + c16
  const unsigned short* bp = W3g + (size_t)(wave * 64 + c16) * 32 + g * 8;

  f32x4 acc1[4][4] = {};

  // prologue: stage tile 0 into buf0
  {
    f32x4 p0 = *(const f32x4*)(aG);
    f32x4 p1 = *(const f32x4*)(aG + 4);
    f32x4 p2 = *(const f32x4*)(aG + 8);
    f32x4 p3 = *(const f32x4*)(aG + 12);
    *(short8*)stW0 = pk8(p0, p1);
    *(short8*)stW1 = pk8(p2, p3);
  }
  __syncthreads();

  #pragma unroll
  for (int ks = 0; ks < 12; ++ks) {
    const int buf = ks & 1;
    // 1) B(ks): 8 fast L2 loads, FIRST in the VMEM FIFO
    short8 B_[8];
    #pragma unroll
    for (int sub = 0; sub < 2; ++sub)
      #pragma unroll
      for (int fn = 0; fn < 4; ++fn)
        B_[sub * 4 + fn] =
            *(const short8*)(bp + (size_t)(ks * 2 + sub) * 8192 + fn * 512);
    __builtin_amdgcn_sched_barrier(0);
    // 2) A(ks+1): 4 slow HBM loads, SECOND in FIFO (stay in flight over MFMA)
    f32x4 av0, av1, av2, av3;
    if (ks < 11) {
      const float* p = aG + (size_t)(ks + 1) * 64;
      av0 = *(const f32x4*)(p);
      av1 = *(const f32x4*)(p + 4);
      av2 = *(const f32x4*)(p + 8);
      av3 = *(const f32x4*)(p + 12);
    }
    __builtin_amdgcn_sched_barrier(0);
    // 3) compute tile ks from LDS buf (compiler: counted lgkmcnt + vmcnt(4) for B)
    #pragma unroll
    for (int sub = 0; sub < 2; ++sub) {
      #pragma unroll
      for (int fm = 0; fm < 4; ++fm) {
        const int r = fm * 16 + c16;
        short8 ah = *(const short8*)&u.stg[buf][r][((sub * 4 + g) ^ (r & 7)) * 8];
        #pragma unroll
        for (int fn = 0; fn < 4; ++fn)
          acc1[fm][fn] = mfma16(ah, B_[sub * 4 + fn], acc1[fm][fn]);
      }
    }
    __builtin_amdgcn_sched_barrier(0);
    // 4) write A(ks+1) -> buf^1 (auto vmcnt for av; queue empty at barrier)
    if (ks < 11) {
      const int nb = (buf ^ 1) * 4096;  // ushorts per buffer
      *(short8*)(stW0 + nb) = pk8(av0, av1);
      *(short8*)(stW1 + nb) = pk8(av2, av3);
      __syncthreads();
    }
  }
  __syncthreads();  // all waves done with stg before prod overwrite

  // ---- epilogue 1: prod = (l3 + b3) * l1 * l2 -> bf16 swizzled LDS ----
  #pragma unroll
  for (int fm = 0; fm < 4; ++fm) {
    #pragma unroll
    for (int r = 0; r < 4; ++r) {
      const int m = fm * 16 + g * 4 + r;
      const float* l2row = l2p + (size_t)(b * 128 + j0 + m) * 256;
      #pragma unroll
      for (int fn = 0; fn < 4; ++fn) {
        const int col = wave * 64 + fn * 16 + c16;
        float v = (acc1[fm][fn][r] + b3s[col]) * l1s[col] * l2row[col];
        u.prod[m][col ^ ((m & 7) << 3)] = f2bf(v);
      }
    }
  }
  __syncthreads();

  // ---- GEMM2: f = prod @ Web^T (Weg fragment-major) ----
  f32x4 acc2[4][4] = {};
  #pragma unroll
  for (int kk = 0; kk < 8; ++kk) {
    short8 a2[4];
    #pragma unroll
    for (int fm = 0; fm < 4; ++fm) {
      const int m = fm * 16 + c16;
      a2[fm] = *(const short8*)&u.prod[m][(kk * 32 + g * 8) ^ ((m & 7) << 3)];
    }
    #pragma unroll
    for (int fn = 0; fn < 4; ++fn) {
      const int n = wave * 64 + fn * 16 + c16;
      short8 bfr = *(const short8*)&Weg[(size_t)((kk * 256 + n) * 4 + g) * 8];
      #pragma unroll
      for (int fm = 0; fm < 4; ++fm)
        acc2[fm][fn] = mfma16(a2[fm], bfr, acc2[fm][fn]);
    }
  }

  // ---- LN stats: per-row sum/sumsq; 16-lane shfl reduce + cross-wave LDS ----
  #pragma unroll
  for (int fm = 0; fm < 4; ++fm) {
    #pragma unroll
    for (int r = 0; r < 4; ++r) {
      float s1 = 0.f, s2 = 0.f;
      #pragma unroll
      for (int fn = 0; fn < 4; ++fn) {
        const int col = wave * 64 + fn * 16 + c16;
        float v = acc2[fm][fn][r] + bes[col];
        s1 += v; s2 += v * v;
      }
      #pragma unroll
      for (int off = 1; off < 16; off <<= 1) {
        s1 += __shfl_xor(s1, off);
        s2 += __shfl_xor(s2, off);
      }
      if (c16 == 0) {
        const int m = fm * 16 + g * 4 + r;
        ps[m][wave] = s1; pq[m][wave] = s2;
      }
    }
  }
  __syncthreads();
  if (tid < 64) {
    float s = ps[tid][0] + ps[tid][1] + ps[tid][2] + ps[tid][3];
    float q = pq[tid][0] + pq[tid][1] + pq[tid][2] + pq[tid][3];
    float mu = s * 0.00390625f;
    float var = q * 0.00390625f - mu * mu;
    mus[tid] = mu;
    rss[tid] = rsqrtf(var + 1e-6f);
  }
  __syncthreads();

  // ---- store: (f - mu)*rs*g + b ----
  #pragma unroll
  for (int fm = 0; fm < 4; ++fm) {
    #pragma unroll
    for (int r = 0; r < 4; ++r) {
      const int m = fm * 16 + g * 4 + r;
      const float mu = mus[m], rs = rss[m];
      float* orow = out + (size_t)(R0 + m) * 256;
      #pragma unroll
      for (int fn = 0; fn < 4; ++fn) {
        const int col = wave * 64 + fn * 16 + c16;
        float v = acc2[fm][fn][r] + bes[col];
        orow[col] = (v - mu) * rs * gs[col] + bsh[col];
      }
    }
  }
}

extern "C" void kernel_launch(void* const* d_in, const int* in_sizes, int n_in,
                              void* d_out, int out_size, void* d_ws, size_t ws_size,
                              hipStream_t stream) {
  const float* sub = (const float*)d_in[0];
  const float* obj = (const float*)d_in[1];
  const float* rel = (const float*)d_in[2];
  const float* W1 = (const float*)d_in[3];
  const float* b1 = (const float*)d_in[4];
  const float* W2 = (const float*)d_in[5];
  const float* b2 = (const float*)d_in[6];
  const float* W3 = (const float*)d_in[7];
  const float* b3 = (const float*)d_in[8];
  const float* We = (const float*)d_in[9];
  const float* be = (const float*)d_in[10];
  const float* lng = (const float*)d_in[11];
  const float* lnb = (const float*)d_in[12];
  float* out = (float*)d_out;

  float* ws = (float*)d_ws;
  float* l1p = ws;
  float* l2p = ws + 262144;
  unsigned short* W3g = (unsigned short*)(ws + 524288);
  unsigned short* Weg = W3g + 196608;

  prep_all<<<1280, 256, 0, stream>>>(sub, obj, W1, b1, W2, b2, W3, We, l1p, l2p, W3g, Weg);
  fused_main<<<2048, 256, 0, stream>>>(rel, l1p, l2p, W3g, Weg, b3, be, lng, lnb, out);
}

// Round 9
// 203.668 us; speedup vs baseline: 2.0221x; 1.0393x over previous
//
#include <hip/hip_runtime.h>
#include <hip/hip_bf16.h>
#include <cstddef>

// BS=8, NE=128, ENT=768, REL=768, RANK=256, OUT=256
// M = 131072 rows; rel row-major [b][i][j][768]
// ws: l1 [1024*256 f32] | l2 [1024*256 f32] | W3g [196608 bf16 frag] | Weg [65536 bf16 frag]
// Fragment-major B panels: flat = ((kq*256 + n)*4 + g)*8 + e (kq=k/32, g=(k/8)%4, e=k%8)
//
// fused_main K-loop (R8 + depth-2 A-prefetch + raw barriers):
//  - A(rel) reg-staged 2 generations deep: issue A(k+2) at iter k, ds_write
//    A(k+1) at iter k (bf16 cvt on write side), consume tile k from LDS.
//    A latency window ~2 iterations; >=16KB/block in flight.
//  - B(W3g) frag-major, 8 L2 loads issued FIRST each iter (fast before slow;
//    R5/R7 FIFO lesson); compiler's counted vmcnt(4) retires [A(k+1),B(k)]
//    leaving A(k+2) in flight.
//  - In-loop barrier is raw s_barrier + lgkmcnt(0) ONLY - never vmcnt(0)
//    (the __syncthreads vmcnt drain was R8's residual stall).
//  - LDS layout/read pattern identical to R8 (measured ~1M conflicts).

typedef __attribute__((ext_vector_type(8))) short short8;
typedef __attribute__((ext_vector_type(4))) float f32x4;

__device__ __forceinline__ unsigned short f2bf(float x) {
  union { float f; unsigned u; } v; v.f = x;
  unsigned r = (v.u + 0x7FFFu + ((v.u >> 16) & 1u)) >> 16;  // RNE
  return (unsigned short)r;
}
__device__ __forceinline__ unsigned short cvt1(float x) {
  return __bfloat16_as_ushort(__float2bfloat16(x));  // pairs to v_cvt_pk_bf16_f32
}
__device__ __forceinline__ f32x4 mfma16(short8 a, short8 b, f32x4 c) {
  return __builtin_amdgcn_mfma_f32_16x16x32_bf16(a, b, c, 0, 0, 0);
}
__device__ __forceinline__ short8 pk8(f32x4 x, f32x4 y) {
  short8 s;
  s[0] = (short)cvt1(x[0]); s[1] = (short)cvt1(x[1]);
  s[2] = (short)cvt1(x[2]); s[3] = (short)cvt1(x[3]);
  s[4] = (short)cvt1(y[0]); s[5] = (short)cvt1(y[1]);
  s[6] = (short)cvt1(y[2]); s[7] = (short)cvt1(y[3]);
  return s;
}

// ---------------- prep (grid 1280) -------------------------------------------
__global__ __launch_bounds__(256) void prep_all(
    const float* __restrict__ sub, const float* __restrict__ obj,
    const float* __restrict__ W1, const float* __restrict__ b1,
    const float* __restrict__ W2, const float* __restrict__ b2,
    const float* __restrict__ W3, const float* __restrict__ We,
    float* __restrict__ l1p, float* __restrict__ l2p,
    unsigned short* __restrict__ W3g, unsigned short* __restrict__ Weg) {
  const int tid = threadIdx.x;
  if (blockIdx.x >= 256) {
    int idx = (blockIdx.x - 256) * 256 + tid;
    if (idx < 196608) {
      int n = idx / 768, k = idx % 768;
      int f = ((k >> 5) * 256 + n) * 32 + ((k >> 3) & 3) * 8 + (k & 7);
      W3g[f] = f2bf(W3[idx]);
    }
    int j = idx - 196608;
    if (j >= 0 && j < 65536) {
      int n = j / 256, k = j % 256;
      int f = ((k >> 5) * 256 + n) * 32 + ((k >> 3) & 3) * 8 + (k & 7);
      Weg[f] = f2bf(We[j]);
    }
    return;
  }
  const int half = blockIdx.x >> 7;
  const float* x = half ? obj : sub;
  const float* W = half ? W2 : W1;
  const float* bias = half ? b2 : b1;
  float* outp = half ? l2p : l1p;

  __shared__ float xs[8][768];
  const int R0 = (blockIdx.x & 127) * 8;
  #pragma unroll
  for (int c = 0; c < 6; ++c) {
    int f4i = c * 256 + tid;
    int row = f4i / 192;
    int c4 = f4i % 192;
    *(float4*)&xs[row][c4 * 4] = *(const float4*)&x[(size_t)(R0 + row) * 768 + c4 * 4];
  }
  __syncthreads();
  const int col = tid;
  const float* Wr = W + (size_t)col * 768;
  float a[8] = {0.f, 0.f, 0.f, 0.f, 0.f, 0.f, 0.f, 0.f};
  for (int k4 = 0; k4 < 192; ++k4) {
    float4 wv = *(const float4*)&Wr[k4 * 4];
    #pragma unroll
    for (int r = 0; r < 8; ++r) {
      float4 xv = *(const float4*)&xs[r][k4 * 4];
      a[r] += wv.x * xv.x + wv.y * xv.y + wv.z * xv.z + wv.w * xv.w;
    }
  }
  float bb = bias[col];
  #pragma unroll
  for (int r = 0; r < 8; ++r)
    outp[(size_t)(R0 + r) * 256 + col] = a[r] + bb;
}

// ---------------- fused main -------------------------------------------------
__global__ __launch_bounds__(256, 3) void fused_main(
    const float* __restrict__ rel, const float* __restrict__ l1p,
    const float* __restrict__ l2p, const unsigned short* __restrict__ W3g,
    const unsigned short* __restrict__ Weg, const float* __restrict__ b3,
    const float* __restrict__ be, const float* __restrict__ lng,
    const float* __restrict__ lnb, float* __restrict__ out) {
  __shared__ union U {
    unsigned short stg[2][64][64];  // 16 KB bf16 staging (R2/R8 layout, clean)
    unsigned short prod[64][256];   // 32 KB
  } u;
  __shared__ float l1s[256], b3s[256], bes[256], gs[256], bsh[256];
  __shared__ float ps[64][4], pq[64][4], mus[64], rss[64];

  const int tid = threadIdx.x;
  const int wave = tid >> 6, lane = tid & 63;
  const int g = lane >> 4, c16 = lane & 15;

  // XCD-bijective swizzle (2048 % 8 == 0)
  const int bid = (blockIdx.x & 7) * 256 + (blockIdx.x >> 3);
  const int R0 = bid * 64;
  const int b = R0 >> 14;
  const int rem = R0 & 16383;
  const int i = rem >> 7;
  const int j0 = rem & 127;  // 0 or 64

  const float* relBase = rel + (size_t)((b * 128 + i) * 128 + j0) * 768;

  l1s[tid] = l1p[(b * 128 + i) * 256 + tid];
  b3s[tid] = b3[tid];
  bes[tid] = be[tid];
  gs[tid] = lng[tid];
  bsh[tid] = lnb[tid];

  // ---- staging geometry: wave owns rows wave*16 .. wave*16+15.
  // lane: row rr = wave*16 + (lane>>2), 16-f32 chunk c4 = lane&3.
  // LDS ushort row [64]: 8 units of 16B; write units (c4*2+h) ^ (rr&7).
  const int sr4 = lane >> 2, c4 = lane & 3;
  const int rr = wave * 16 + sr4;
  const float* aG = relBase + (size_t)rr * 768 + c4 * 16;
  unsigned short* stW0 = &u.stg[0][rr][((c4 * 2) ^ (rr & 7)) * 8];
  unsigned short* stW1 = &u.stg[0][rr][((c4 * 2 + 1) ^ (rr & 7)) * 8];

  // B: fragment-major W3g; n = wave*64 + fn*16 + c16
  const unsigned short* bp = W3g + (size_t)(wave * 64 + c16) * 32 + g * 8;

  f32x4 acc1[4][4] = {};
  f32x4 av[2][4];  // A data in flight / awaiting LDS write (static idx, full unroll)

#define RAW_BARRIER                                           \
  do {                                                        \
    __builtin_amdgcn_sched_barrier(0);                        \
    asm volatile("s_waitcnt lgkmcnt(0)" ::: "memory");        \
    __builtin_amdgcn_sched_barrier(0);                        \
    __builtin_amdgcn_s_barrier();                             \
    __builtin_amdgcn_sched_barrier(0);                        \
  } while (0)

  // ---- prologue: A(0) -> buf0 (via av[1] as temp), A(1) -> av[0] in flight
  {
    const float* p0 = aG;
    av[1][0] = *(const f32x4*)(p0);
    av[1][1] = *(const f32x4*)(p0 + 4);
    av[1][2] = *(const f32x4*)(p0 + 8);
    av[1][3] = *(const f32x4*)(p0 + 12);
    const float* p1 = aG + 64;
    av[0][0] = *(const f32x4*)(p1);
    av[0][1] = *(const f32x4*)(p1 + 4);
    av[0][2] = *(const f32x4*)(p1 + 8);
    av[0][3] = *(const f32x4*)(p1 + 12);
    // compiler inserts vmcnt(4): retires A(0), leaves A(1) in flight
    *(short8*)stW0 = pk8(av[1][0], av[1][1]);
    *(short8*)stW1 = pk8(av[1][2], av[1][3]);
  }
  RAW_BARRIER;

  #pragma unroll
  for (int ks = 0; ks < 12; ++ks) {
    const int buf = ks & 1;
    // 1) B(ks): 8 fast L2 loads, FIRST in FIFO
    short8 B_[8];
    #pragma unroll
    for (int sub = 0; sub < 2; ++sub)
      #pragma unroll
      for (int fn = 0; fn < 4; ++fn)
        B_[sub * 4 + fn] =
            *(const short8*)(bp + (size_t)(ks * 2 + sub) * 8192 + fn * 512);
    __builtin_amdgcn_sched_barrier(0);
    // 2) A(ks+2): 4 slow HBM loads, SECOND in FIFO (2-deep prefetch)
    if (ks <= 9) {
      const float* p = aG + (size_t)(ks + 2) * 64;
      av[(ks + 1) & 1][0] = *(const f32x4*)(p);
      av[(ks + 1) & 1][1] = *(const f32x4*)(p + 4);
      av[(ks + 1) & 1][2] = *(const f32x4*)(p + 8);
      av[(ks + 1) & 1][3] = *(const f32x4*)(p + 12);
    }
    __builtin_amdgcn_sched_barrier(0);
    // 3) compute tile ks from LDS buf; compiler waits vmcnt(4) for B
    //    (retiring A(ks+1) exactly in time for step 4)
    #pragma unroll
    for (int sub = 0; sub < 2; ++sub) {
      #pragma unroll
      for (int fm = 0; fm < 4; ++fm) {
        const int r = fm * 16 + c16;
        short8 ah = *(const short8*)&u.stg[buf][r][((sub * 4 + g) ^ (r & 7)) * 8];
        #pragma unroll
        for (int fn = 0; fn < 4; ++fn)
          acc1[fm][fn] = mfma16(ah, B_[sub * 4 + fn], acc1[fm][fn]);
      }
    }
    __builtin_amdgcn_sched_barrier(0);
    // 4) write A(ks+1) (retired) -> buf^1; raw barrier (lgkm only, vmcnt live)
    if (ks <= 10) {
      const int nb = (buf ^ 1) * 4096;  // ushorts per buffer
      *(short8*)(stW0 + nb) = pk8(av[ks & 1][0], av[ks & 1][1]);
      *(short8*)(stW1 + nb) = pk8(av[ks & 1][2], av[ks & 1][3]);
      RAW_BARRIER;
    }
  }
  __syncthreads();  // full drain fine here; queue empty. Protects stg->prod reuse

  // ---- epilogue 1: prod = (l3 + b3) * l1 * l2 -> bf16 swizzled LDS ----
  #pragma unroll
  for (int fm = 0; fm < 4; ++fm) {
    #pragma unroll
    for (int r = 0; r < 4; ++r) {
      const int m = fm * 16 + g * 4 + r;
      const float* l2row = l2p + (size_t)(b * 128 + j0 + m) * 256;
      #pragma unroll
      for (int fn = 0; fn < 4; ++fn) {
        const int col = wave * 64 + fn * 16 + c16;
        float v = (acc1[fm][fn][r] + b3s[col]) * l1s[col] * l2row[col];
        u.prod[m][col ^ ((m & 7) << 3)] = f2bf(v);
      }
    }
  }
  __syncthreads();

  // ---- GEMM2: f = prod @ Web^T (Weg fragment-major) ----
  f32x4 acc2[4][4] = {};
  #pragma unroll
  for (int kk = 0; kk < 8; ++kk) {
    short8 a2[4];
    #pragma unroll
    for (int fm = 0; fm < 4; ++fm) {
      const int m = fm * 16 + c16;
      a2[fm] = *(const short8*)&u.prod[m][(kk * 32 + g * 8) ^ ((m & 7) << 3)];
    }
    #pragma unroll
    for (int fn = 0; fn < 4; ++fn) {
      const int n = wave * 64 + fn * 16 + c16;
      short8 bfr = *(const short8*)&Weg[(size_t)((kk * 256 + n) * 4 + g) * 8];
      #pragma unroll
      for (int fm = 0; fm < 4; ++fm)
        acc2[fm][fn] = mfma16(a2[fm], bfr, acc2[fm][fn]);
    }
  }

  // ---- LN stats: per-row sum/sumsq; 16-lane shfl reduce + cross-wave LDS ----
  #pragma unroll
  for (int fm = 0; fm < 4; ++fm) {
    #pragma unroll
    for (int r = 0; r < 4; ++r) {
      float s1 = 0.f, s2 = 0.f;
      #pragma unroll
      for (int fn = 0; fn < 4; ++fn) {
        const int col = wave * 64 + fn * 16 + c16;
        float v = acc2[fm][fn][r] + bes[col];
        s1 += v; s2 += v * v;
      }
      #pragma unroll
      for (int off = 1; off < 16; off <<= 1) {
        s1 += __shfl_xor(s1, off);
        s2 += __shfl_xor(s2, off);
      }
      if (c16 == 0) {
        const int m = fm * 16 + g * 4 + r;
        ps[m][wave] = s1; pq[m][wave] = s2;
      }
    }
  }
  __syncthreads();
  if (tid < 64) {
    float s = ps[tid][0] + ps[tid][1] + ps[tid][2] + ps[tid][3];
    float q = pq[tid][0] + pq[tid][1] + pq[tid][2] + pq[tid][3];
    float mu = s * 0.00390625f;
    float var = q * 0.00390625f - mu * mu;
    mus[tid] = mu;
    rss[tid] = rsqrtf(var + 1e-6f);
  }
  __syncthreads();

  // ---- store: (f - mu)*rs*g + b ----
  #pragma unroll
  for (int fm = 0; fm < 4; ++fm) {
    #pragma unroll
    for (int r = 0; r < 4; ++r) {
      const int m = fm * 16 + g * 4 + r;
      const float mu = mus[m], rs = rss[m];
      float* orow = out + (size_t)(R0 + m) * 256;
      #pragma unroll
      for (int fn = 0; fn < 4; ++fn) {
        const int col = wave * 64 + fn * 16 + c16;
        float v = acc2[fm][fn][r] + bes[col];
        orow[col] = (v - mu) * rs * gs[col] + bsh[col];
      }
    }
  }
#undef RAW_BARRIER
}

extern "C" void kernel_launch(void* const* d_in, const int* in_sizes, int n_in,
                              void* d_out, int out_size, void* d_ws, size_t ws_size,
                              hipStream_t stream) {
  const float* sub = (const float*)d_in[0];
  const float* obj = (const float*)d_in[1];
  const float* rel = (const float*)d_in[2];
  const float* W1 = (const float*)d_in[3];
  const float* b1 = (const float*)d_in[4];
  const float* W2 = (const float*)d_in[5];
  const float* b2 = (const float*)d_in[6];
  const float* W3 = (const float*)d_in[7];
  const float* b3 = (const float*)d_in[8];
  const float* We = (const float*)d_in[9];
  const float* be = (const float*)d_in[10];
  const float* lng = (const float*)d_in[11];
  const float* lnb = (const float*)d_in[12];
  float* out = (float*)d_out;

  float* ws = (float*)d_ws;
  float* l1p = ws;
  float* l2p = ws + 262144;
  unsigned short* W3g = (unsigned short*)(ws + 524288);
  unsigned short* Weg = W3g + 196608;

  prep_all<<<1280, 256, 0, stream>>>(sub, obj, W1, b1, W2, b2, W3, We, l1p, l2p, W3g, Weg);
  fused_main<<<2048, 256, 0, stream>>>(rel, l1p, l2p, W3g, Weg, b3, be, lng, lnb, out);
}